// Round 12
// baseline (120.272 us; speedup 1.0000x reference)
//
#include <hip/hip_runtime.h>

namespace {

typedef float v2f __attribute__((ext_vector_type(2)));
typedef float v4f __attribute__((ext_vector_type(4)));

constexpr int kB = 4, kCin = 4, kCout = 4;
constexpr int kD1 = 32, kD2 = 32, kH = 64, kW = 64;
constexpr int kHO = 32, kWO = 32;
constexpr int kSlice = kH * kW;                       // 4096
constexpr size_t kCiStride = (size_t)kD1 * kD2 * kSlice;

__global__ __launch_bounds__(256)
void conv4d_strang(const float* __restrict__ x, const float* __restrict__ w,
                   const float* __restrict__ bias, float* __restrict__ y)
{
    // XCD-chunked decode: chunk=(b, h-half) -> each XCD owns a private 32MB
    // of x. Serpentine v sweep keeps halo slices L2-hot across transitions.
    const unsigned orig  = blockIdx.x;       // 0..4095
    const unsigned chunk = orig & 7;         // XCD id under round-robin
    const unsigned rem   = orig >> 3;        // 0..511
    const int b  = chunk >> 1;
    const int ht = chunk & 1;
    const int tu = rem >> 5;                 // 0..15  -> u0 = 2*tu
    const int vr = rem & 31;
    const int v  = (tu & 1) ? (31 - vr) : vr;   // serpentine
    const int u0 = 2 * tu;                   // 2x1 (u,v) register tile

    const int wq = threadIdx.x;              // 0..15 -> outputs 2wq, 2wq+1
    const int hy = threadIdx.y;              // 0..15
    const int ho = ht * 16 + hy;             // 0..31
    const int toff = (2 * ho) * kW + 4 * wq; // per-lane ELEMENT offset

    // acc[uu][co][wo-sub], v2f lanes = (kw-even, kw-odd) partials. 32 VGPRs.
    v2f acc[2][kCout][2];
    #pragma unroll
    for (int co = 0; co < kCout; ++co) {
        const float bb = bias[co];
        #pragma unroll
        for (int uu = 0; uu < 2; ++uu) {
            acc[uu][co][0] = (v2f){bb, 0.f};
            acc[uu][co][1] = (v2f){bb, 0.f};
        }
    }

    // UNIFORM bases: slice/ci bases stay in SGPRs; per-lane toff applied only
    // at the dereference -> global_load_dwordx4 v, v_toff, s[base] (+imm).
    const float* xu = x + (size_t)(b * kCin) * kCiStride;

    // Depth-2 ci pipeline: two named load-buffer pairs, load-ahead-by-one.
#define LD(R0, R1, CI)                                                       \
    {                                                                        \
        const float* sc_ = su + (size_t)(CI) * kCiStride;                    \
        R0 = *reinterpret_cast<const v4f*>(sc_ + toff);                      \
        R1 = *reinterpret_cast<const v4f*>(sc_ + toff + kW);                 \
    }
#define FMA(R0, R1, CI)                                                      \
    {                                                                        \
        const v2f xa0 = R0.xy, xa1 = R0.zw;                                  \
        const v2f xb0 = R1.xy, xb1 = R1.zw;                                  \
        _Pragma("unroll")                                                    \
        for (int uu = 0; uu < 2; ++uu) {                                     \
            const int ku = e1 - uu;                                          \
            if (ku < 0 || ku > 2) continue;        /* compile-time */        \
            _Pragma("unroll")                                                \
            for (int co = 0; co < kCout; ++co) {                             \
                const float* wp =                                            \
                    w + (((co * kCin + (CI)) * 3 + ku) * 3 + e2) * 4;        \
                const v2f w01 = {wp[0], wp[1]};    /* kh=0 */                \
                const v2f w23 = {wp[2], wp[3]};    /* kh=1 */                \
                acc[uu][co][0] =                                             \
                    __builtin_elementwise_fma(xa0, w01, acc[uu][co][0]);     \
                acc[uu][co][0] =                                             \
                    __builtin_elementwise_fma(xb0, w23, acc[uu][co][0]);     \
                acc[uu][co][1] =                                             \
                    __builtin_elementwise_fma(xa1, w01, acc[uu][co][1]);     \
                acc[uu][co][1] =                                             \
                    __builtin_elementwise_fma(xb1, w23, acc[uu][co][1]);     \
            }                                                                \
        }                                                                    \
    }

    #pragma unroll
    for (int e1 = 0; e1 < 4; ++e1) {
        const int d1 = u0 + e1 - 1;
        if ((unsigned)d1 >= (unsigned)kD1) continue;      // wave-uniform
        #pragma unroll
        for (int e2 = 0; e2 < 3; ++e2) {
            const int d2 = v + e2 - 1;
            if ((unsigned)d2 >= (unsigned)kD2) continue;  // wave-uniform
            const float* su = xu + (size_t)(d1 * kD2 + d2) * kSlice;  // uniform
            v4f a0, a1, b0, b1;
            LD(a0, a1, 0); LD(b0, b1, 1);
            FMA(a0, a1, 0); LD(a0, a1, 2);
            FMA(b0, b1, 1); LD(b0, b1, 3);
            FMA(a0, a1, 2);
            FMA(b0, b1, 3);
        }
    }
#undef LD
#undef FMA

    // Non-temporal stores: y is never re-read -> don't evict x from L2/L3.
    #pragma unroll
    for (int co = 0; co < kCout; ++co)
        #pragma unroll
        for (int uu = 0; uu < 2; ++uu) {
            v2f o;
            o.x = acc[uu][co][0].x + acc[uu][co][0].y;
            o.y = acc[uu][co][1].x + acc[uu][co][1].y;
            float* yp = y
                + ((((size_t)(b * kCout + co) * kD1 + (u0 + uu)) * kD2 + v) * kHO + ho) * kWO
                + 2 * wq;
            __builtin_nontemporal_store(o, reinterpret_cast<v2f*>(yp));
        }
}

}  // namespace

extern "C" void kernel_launch(void* const* d_in, const int* in_sizes, int n_in,
                              void* d_out, int out_size, void* d_ws, size_t ws_size,
                              hipStream_t stream) {
    const float* x    = (const float*)d_in[0];
    const float* w    = (const float*)d_in[1];
    const float* bias = (const float*)d_in[2];
    float* y          = (float*)d_out;

    dim3 block(16, 16, 1);
    dim3 grid(kB * 2 * 16 * 32, 1, 1);     // 4096 blocks, decoded in-kernel
    hipLaunchKernelGGL(conv4d_strang, grid, block, 0, stream, x, w, bias, y);
}

// Round 13
// 90.796 us; speedup vs baseline: 1.3246x; 1.3246x over previous
//
#include <hip/hip_runtime.h>

namespace {

typedef float v2f __attribute__((ext_vector_type(2)));
typedef float v4f __attribute__((ext_vector_type(4)));

constexpr int kB = 4, kCin = 4, kCout = 4;
constexpr int kD1 = 32, kD2 = 32, kH = 64, kW = 64;
constexpr int kHO = 32, kWO = 32;
constexpr int kSlice = kH * kW;                       // 4096
constexpr size_t kCiStride = (size_t)kD1 * kD2 * kSlice;
constexpr size_t kD1Stride = (size_t)kD2 * kSlice;

__global__ __launch_bounds__(256)
void conv4d_strang(const float* __restrict__ x, const float* __restrict__ w,
                   const float* __restrict__ bias, float* __restrict__ y)
{
    // XCD-chunked decode: chunk=(b, h-half) -> each XCD owns a private 32MB
    // of x. Serpentine v sweep keeps halo slices L2-hot across transitions.
    const unsigned orig  = blockIdx.x;       // 0..4095
    const unsigned chunk = orig & 7;         // XCD id under round-robin
    const unsigned rem   = orig >> 3;        // 0..511
    const int b  = chunk >> 1;
    const int ht = chunk & 1;
    const int tu = rem >> 5;                 // 0..15  -> u0 = 2*tu
    const int vr = rem & 31;
    const int v  = (tu & 1) ? (31 - vr) : vr;   // serpentine
    const int u0 = 2 * tu;                   // 2x1 (u,v) register tile

    const int wq = threadIdx.x;              // 0..15 -> outputs 2wq, 2wq+1
    const int hy = threadIdx.y;              // 0..15
    const int ho = ht * 16 + hy;             // 0..31
    const int toff = (2 * ho) * kW + 4 * wq; // per-lane ELEMENT offset

    // acc[uu][co][wo-sub], v2f lanes = (kw-even, kw-odd) partials. 32 VGPRs.
    v2f acc[2][kCout][2];
    #pragma unroll
    for (int co = 0; co < kCout; ++co) {
        const float bb = bias[co];
        #pragma unroll
        for (int uu = 0; uu < 2; ++uu) {
            acc[uu][co][0] = (v2f){bb, 0.f};
            acc[uu][co][1] = (v2f){bb, 0.f};
        }
    }

    // UNIFORM bases: slice/ci bases stay in SGPRs; per-lane toff applied only
    // at the dereference -> global_load_dwordx4 v, v_toff, s[base] (+imm).
    const float* xu = x + (size_t)(b * kCin) * kCiStride;

    // Loop order ci -> e2(=kv) -> e1: weights for (ci,kv) hoisted into 12
    // uniform dwordx4 (48 SGPRs), loaded ONCE per (ci,e2). The hot e1 loop
    // then has ZERO scalar-mem ops -> no out-of-order-SMEM lgkmcnt(0)
    // drains between FMAs; x-loads pipeline freely on vmcnt.
    #pragma unroll
    for (int ci = 0; ci < kCin; ++ci) {
        const float* xc = xu + (size_t)ci * kCiStride;          // uniform
        #pragma unroll
        for (int e2 = 0; e2 < 3; ++e2) {                        // kv == e2
            const int d2 = v + e2 - 1;
            if ((unsigned)d2 >= (unsigned)kD2) continue;        // wave-uniform
            // Hoisted weights wk[ku][co]: fully-constant offsets -> s_load.
            v4f wk[3][kCout];
            #pragma unroll
            for (int ku = 0; ku < 3; ++ku)
                #pragma unroll
                for (int co = 0; co < kCout; ++co)
                    wk[ku][co] = *reinterpret_cast<const v4f*>(
                        w + (((co * kCin + ci) * 3 + ku) * 3 + e2) * 4);

            const float* sbase = xc + (size_t)d2 * kSlice;      // uniform
            #pragma unroll
            for (int e1 = 0; e1 < 4; ++e1) {
                const int d1 = u0 + e1 - 1;
                if ((unsigned)d1 >= (unsigned)kD1) continue;    // wave-uniform
                const float* sc = sbase + (size_t)d1 * kD1Stride;  // uniform
                const v4f r0 = *reinterpret_cast<const v4f*>(sc + toff);
                const v4f r1 = *reinterpret_cast<const v4f*>(sc + toff + kW);
                const v2f xa0 = r0.xy, xa1 = r0.zw;
                const v2f xb0 = r1.xy, xb1 = r1.zw;
                #pragma unroll
                for (int uu = 0; uu < 2; ++uu) {
                    const int ku = e1 - uu;
                    if (ku < 0 || ku > 2) continue;             // compile-time
                    #pragma unroll
                    for (int co = 0; co < kCout; ++co) {
                        const v2f w01 = wk[ku][co].xy;          // kh=0 (SGPR pair)
                        const v2f w23 = wk[ku][co].zw;          // kh=1
                        acc[uu][co][0] =
                            __builtin_elementwise_fma(xa0, w01, acc[uu][co][0]);
                        acc[uu][co][0] =
                            __builtin_elementwise_fma(xb0, w23, acc[uu][co][0]);
                        acc[uu][co][1] =
                            __builtin_elementwise_fma(xa1, w01, acc[uu][co][1]);
                        acc[uu][co][1] =
                            __builtin_elementwise_fma(xb1, w23, acc[uu][co][1]);
                    }
                }
            }
        }
    }

    // Non-temporal stores: y is never re-read -> don't evict x from L2/L3.
    #pragma unroll
    for (int co = 0; co < kCout; ++co)
        #pragma unroll
        for (int uu = 0; uu < 2; ++uu) {
            v2f o;
            o.x = acc[uu][co][0].x + acc[uu][co][0].y;
            o.y = acc[uu][co][1].x + acc[uu][co][1].y;
            float* yp = y
                + ((((size_t)(b * kCout + co) * kD1 + (u0 + uu)) * kD2 + v) * kHO + ho) * kWO
                + 2 * wq;
            __builtin_nontemporal_store(o, reinterpret_cast<v2f*>(yp));
        }
}

}  // namespace

extern "C" void kernel_launch(void* const* d_in, const int* in_sizes, int n_in,
                              void* d_out, int out_size, void* d_ws, size_t ws_size,
                              hipStream_t stream) {
    const float* x    = (const float*)d_in[0];
    const float* w    = (const float*)d_in[1];
    const float* bias = (const float*)d_in[2];
    float* y          = (float*)d_out;

    dim3 block(16, 16, 1);
    dim3 grid(kB * 2 * 16 * 32, 1, 1);     // 4096 blocks, decoded in-kernel
    hipLaunchKernelGGL(conv4d_strang, grid, block, 0, stream, x, w, bias, y);
}

// Round 14
// 83.167 us; speedup vs baseline: 1.4462x; 1.0917x over previous
//
#include <hip/hip_runtime.h>

namespace {

typedef float v2f __attribute__((ext_vector_type(2)));
typedef float v4f __attribute__((ext_vector_type(4)));

constexpr int kB = 4, kCin = 4, kCout = 4;
constexpr int kD1 = 32, kD2 = 32, kH = 64, kW = 64;
constexpr int kHO = 32, kWO = 32;
constexpr int kSlice = kH * kW;                       // 4096
constexpr size_t kCiStride = (size_t)kD1 * kD2 * kSlice;
constexpr size_t kD1Stride = (size_t)kD2 * kSlice;

__global__ __launch_bounds__(256)
void conv4d_strang(const float* __restrict__ x, const float* __restrict__ w,
                   const float* __restrict__ bias, float* __restrict__ y)
{
    // XCD-chunked decode: chunk=(b, h-half) -> each XCD owns a private 32MB
    // of x. Serpentine tv sweep keeps halo slices L2-hot across transitions.
    const unsigned orig  = blockIdx.x;       // 0..2047
    const unsigned chunk = orig & 7;         // XCD id under round-robin
    const unsigned rem   = orig >> 3;        // 0..255
    const int b  = chunk >> 1;
    const int ht = chunk & 1;
    const int tu = rem >> 4;                 // 0..15
    const int tvr = rem & 15;
    const int tv = (tu & 1) ? (15 - tvr) : tvr;   // serpentine
    const int u0 = 2 * tu, v0 = 2 * tv;      // 2x2 (u,v) register tile

    const int wq = threadIdx.x;              // 0..15 -> outputs 2wq, 2wq+1
    const int hy = threadIdx.y;              // 0..15
    const int ho = ht * 16 + hy;             // 0..31
    const int toff = (2 * ho) * kW + 4 * wq; // per-lane ELEMENT offset

    // acc[uu][vv][co][wo-sub], v2f lanes = (kw-even, kw-odd) partials.
    // 32 x v2f = 64 VGPRs; viable now that addressing is SGPR-based and
    // weights are hoisted (the R4-R8 defects).
    v2f acc[2][2][kCout][2];
    #pragma unroll
    for (int co = 0; co < kCout; ++co) {
        const float bb = bias[co];
        #pragma unroll
        for (int uu = 0; uu < 2; ++uu)
            #pragma unroll
            for (int vv = 0; vv < 2; ++vv) {
                acc[uu][vv][co][0] = (v2f){bb, 0.f};
                acc[uu][vv][co][1] = (v2f){bb, 0.f};
            }
    }

    // UNIFORM bases: slice/ci bases stay in SGPRs; per-lane toff applied only
    // at the dereference -> global_load_dwordx4 v, v_toff, s[base] (+imm).
    const float* xu = x + (size_t)(b * kCin) * kCiStride;

    // Loop order ci -> e2 -> (hoisted weights) -> e1: the hot e1 loop has
    // zero scalar-mem ops -> no out-of-order-SMEM lgkmcnt(0) drains between
    // FMA clusters (the R13 win, preserved).
    #pragma unroll
    for (int ci = 0; ci < kCin; ++ci) {
        const float* xc = xu + (size_t)ci * kCiStride;          // uniform
        #pragma unroll
        for (int e2 = 0; e2 < 4; ++e2) {
            const int d2 = v0 + e2 - 1;
            if ((unsigned)d2 >= (unsigned)kD2) continue;        // wave-uniform
            // Hoisted weights wk[vv][ku][co] for kv=e2-vv (valid entries
            // only): fully-constant offsets -> uniform s_load_dwordx4.
            v4f wk[2][3][kCout];
            #pragma unroll
            for (int vv = 0; vv < 2; ++vv) {
                const int kv = e2 - vv;
                if (kv < 0 || kv > 2) continue;                 // compile-time
                #pragma unroll
                for (int ku = 0; ku < 3; ++ku)
                    #pragma unroll
                    for (int co = 0; co < kCout; ++co)
                        wk[vv][ku][co] = *reinterpret_cast<const v4f*>(
                            w + (((co * kCin + ci) * 3 + ku) * 3 + kv) * 4);
            }

            const float* sbase = xc + (size_t)d2 * kSlice;      // uniform
            #pragma unroll
            for (int e1 = 0; e1 < 4; ++e1) {
                const int d1 = u0 + e1 - 1;
                if ((unsigned)d1 >= (unsigned)kD1) continue;    // wave-uniform
                const float* sc = sbase + (size_t)d1 * kD1Stride;  // uniform
                const v4f r0 = *reinterpret_cast<const v4f*>(sc + toff);
                const v4f r1 = *reinterpret_cast<const v4f*>(sc + toff + kW);
                const v2f xa0 = r0.xy, xa1 = r0.zw;
                const v2f xb0 = r1.xy, xb1 = r1.zw;
                #pragma unroll
                for (int uu = 0; uu < 2; ++uu) {
                    const int ku = e1 - uu;
                    if (ku < 0 || ku > 2) continue;             // compile-time
                    #pragma unroll
                    for (int vv = 0; vv < 2; ++vv) {
                        const int kv = e2 - vv;
                        if (kv < 0 || kv > 2) continue;         // compile-time
                        #pragma unroll
                        for (int co = 0; co < kCout; ++co) {
                            const v2f w01 = wk[vv][ku][co].xy;  // kh=0
                            const v2f w23 = wk[vv][ku][co].zw;  // kh=1
                            acc[uu][vv][co][0] =
                                __builtin_elementwise_fma(xa0, w01, acc[uu][vv][co][0]);
                            acc[uu][vv][co][0] =
                                __builtin_elementwise_fma(xb0, w23, acc[uu][vv][co][0]);
                            acc[uu][vv][co][1] =
                                __builtin_elementwise_fma(xa1, w01, acc[uu][vv][co][1]);
                            acc[uu][vv][co][1] =
                                __builtin_elementwise_fma(xb1, w23, acc[uu][vv][co][1]);
                        }
                    }
                }
            }
        }
    }

    // Non-temporal stores: y is never re-read -> don't evict x from L2/L3.
    #pragma unroll
    for (int co = 0; co < kCout; ++co)
        #pragma unroll
        for (int uu = 0; uu < 2; ++uu)
            #pragma unroll
            for (int vv = 0; vv < 2; ++vv) {
                v2f o;
                o.x = acc[uu][vv][co][0].x + acc[uu][vv][co][0].y;
                o.y = acc[uu][vv][co][1].x + acc[uu][vv][co][1].y;
                float* yp = y
                    + ((((size_t)(b * kCout + co) * kD1 + (u0 + uu)) * kD2 + (v0 + vv)) * kHO + ho) * kWO
                    + 2 * wq;
                __builtin_nontemporal_store(o, reinterpret_cast<v2f*>(yp));
            }
}

}  // namespace

extern "C" void kernel_launch(void* const* d_in, const int* in_sizes, int n_in,
                              void* d_out, int out_size, void* d_ws, size_t ws_size,
                              hipStream_t stream) {
    const float* x    = (const float*)d_in[0];
    const float* w    = (const float*)d_in[1];
    const float* bias = (const float*)d_in[2];
    float* y          = (float*)d_out;

    dim3 block(16, 16, 1);
    dim3 grid(kB * 2 * 16 * 16, 1, 1);     // 2048 blocks, decoded in-kernel
    hipLaunchKernelGGL(conv4d_strang, grid, block, 0, stream, x, w, bias, y);
}